// Round 9
// baseline (194.159 us; speedup 1.0000x reference)
//
#include <hip/hip_runtime.h>
#include <cstdint>
#include <cstddef>

#define B_ 2
#define N_ 2048
#define C_ 256
#define H_ 64
#define W_ 176
#define TW 16
#define NTX 11                    // 176/16 tiles per row
#define NTILES (B_*H_*NTX)        // 1408
#define CAP 1024                  // per-tile list cap (avg ~120, peak well below)
#define G_ 16                     // gaussians per splat chunk
#define SA 260                    // mlp act LDS stride (floats)

typedef short bf16x8 __attribute__((ext_vector_type(8)));
typedef float f32x4  __attribute__((ext_vector_type(4)));

__device__ __forceinline__ short f2bf(float f)   // RNE fp32->bf16
{
    unsigned u = __float_as_uint(f);
    return (short)((u + 0x7FFFu + ((u >> 16) & 1u)) >> 16);
}

// global->LDS direct DMA: each lane moves 16B.
__device__ __forceinline__ void gl_lds16(const float* gsrc, float* ldst)
{
    auto gp = (const __attribute__((address_space(1))) unsigned int*)(uintptr_t)gsrc;
    auto lp = (__attribute__((address_space(3))) unsigned int*)(unsigned int)(uintptr_t)ldst;
    __builtin_amdgcn_global_load_lds(gp, lp, 16, 0, 0);
}

// ---------------------------------------------------------------------------
// Fused param + bin + weight-convert (unchanged from R8).
// ---------------------------------------------------------------------------
__global__ __launch_bounds__(256)
void parambin_kernel(const float* __restrict__ g, const float* __restrict__ intr,
                     const float* __restrict__ w3f, const float* __restrict__ fw1f,
                     const float* __restrict__ fw2f,
                     short* __restrict__ wt3, short* __restrict__ wt4,
                     short* __restrict__ wt5,
                     float* __restrict__ pp, int* __restrict__ counts,
                     int* __restrict__ lists)
{
    const int tid = threadIdx.x;
    const int gid = blockIdx.x * 256 + tid;
    for (int e = gid; e < 163840; e += 131072) {
        if (e < 32768) {
            const int k = e >> 8, n = e & 255;
            wt3[n * 128 + k] = f2bf(w3f[e]);
        } else if (e < 98304) {
            const int i = e - 32768, k = i >> 8, n = i & 255;
            wt4[n * 256 + k] = f2bf(fw1f[i]);
        } else {
            const int i = e - 98304, k = i >> 8, n = i & 255;
            wt5[n * 256 + k] = f2bf(fw2f[i]);
        }
    }
    const int i = blockIdx.x * 8 + (tid >> 5);
    const int j = tid & 31;
    const float* gi = g + (size_t)i * 14;
    const float x = gi[0], y = gi[1], z = gi[2];
    const float s5 = gi[5], s6 = gi[6], wv = gi[12];
    const float k00 = intr[0], k01 = intr[1], k02 = intr[2];
    const float k10 = intr[3], k11 = intr[4], k12 = intr[5];
    const float k20 = intr[6], k21 = intr[7], k22 = intr[8];
    const float projx = k00 * x + k01 * y + k02 * z;
    const float projy = k10 * x + k11 * y + k12 * z;
    const float projz = k20 * x + k21 * y + k22 * z;
    const float inv = 1.f / (projz + 1e-6f);
    const float scale_x = (float)W_ / k02 * 0.5f;
    const float scale_y = (float)H_ / k12 * 0.5f;
    const float px = projx * inv * scale_x;
    const float py = projy * inv * scale_y;
    const bool valid = z > 0.1f;
    const bool inb = (px >= 0.f) && (px < (float)W_) && (py >= 0.f) && (py < (float)H_);
    const bool mask = valid && inb;
    const float sx = fmaxf(s5 * scale_x, 1.f);
    const float sy = fmaxf(s6 * scale_y, 1.f);
    if (j == 0) {
        float4* o = (float4*)(pp + (size_t)i * 8);
        o[0] = make_float4(px, py, 1.f / sx, 1.f / sy);
        o[1] = make_float4(wv, 0.5f * (sx + sy), 0.f, 0.f);
    }
    if (!mask) return;
    const float rx = 3.f * sx, ry = 3.f * sy;
    const int ymin = max(0, (int)floorf(py - ry));
    const int ymax = min(H_ - 1, (int)ceilf(py + ry));
    const int yy = ymin + j;
    if (yy > ymax) return;
    const int tmin = max(0, (int)floorf((px - rx - (float)(TW - 1)) * (1.f / TW)));
    const int tmax = min(NTX - 1, (int)ceilf((px + rx) * (1.f / TW)));
    const int b = i / N_, n = i - b * N_;
    for (int t = tmin; t <= tmax; ++t) {
        const int tile = (b * H_ + yy) * NTX + t;
        const int slot = atomicAdd(&counts[tile], 1);
        if (slot < CAP) lists[(size_t)tile * CAP + slot] = n;
    }
}

// ---------------------------------------------------------------------------
// MFMA helper (unchanged from R8).
// ---------------------------------------------------------------------------
template<int K>
__device__ __forceinline__ void mfma_acc(const short* __restrict__ wt,
                                         const float* actIn, f32x4 (&acc)[4],
                                         int wv_, int quad, int ln15)
{
#pragma unroll
    for (int ks = 0; ks < K / 32; ++ks) {
        const int kb = ks * 32 + quad * 8;
        const float4 a0 = *(const float4*)&actIn[ln15 * SA + kb];
        const float4 a1 = *(const float4*)&actIn[ln15 * SA + kb + 4];
        bf16x8 af = { f2bf(a0.x), f2bf(a0.y), f2bf(a0.z), f2bf(a0.w),
                      f2bf(a1.x), f2bf(a1.y), f2bf(a1.z), f2bf(a1.w) };
#pragma unroll
        for (int tt = 0; tt < 4; ++tt) {
            const int n0 = (wv_ * 4 + tt) * 16;
            const bf16x8 bf = *(const bf16x8*)&wt[(size_t)(n0 + ln15) * K + kb];
            acc[tt] = __builtin_amdgcn_mfma_f32_16x16x32_bf16(af, bf, acc[tt], 0, 0, 0);
        }
    }
}

// ---------------------------------------------------------------------------
// Fused MLP (unchanged from R8): L1/L2 fp32 VALU, L3-L5 bf16 MFMA.
// ---------------------------------------------------------------------------
__global__ __launch_bounds__(256)
void mlp_kernel(const float* __restrict__ g,
                const float* __restrict__ w1, const float* __restrict__ b1,
                const float* __restrict__ w2, const float* __restrict__ b2,
                const short* __restrict__ wt3, const float* __restrict__ b3,
                const short* __restrict__ wt4, const float* __restrict__ fb1,
                const short* __restrict__ wt5, const float* __restrict__ fb2,
                float* __restrict__ ft)
{
    __shared__ __align__(16) float A_[16 * SA];
    __shared__ __align__(16) float Bb[16 * SA];
    const int tid  = threadIdx.x;
    const int row0 = blockIdx.x * 16;
    const int lane = tid & 63;
    const int wv_  = tid >> 6;
    const int quad = lane >> 4;
    const int ln15 = lane & 15;

    if (tid < 224) {
        const int k = tid / 16, m = tid % 16;
        A_[m * SA + k] = g[(size_t)(row0 + m) * 14 + k];
    }
    __syncthreads();

    {   // L1: 14 -> 64, relu
        const int col = tid & 63;
        const int m0  = (tid >> 6) * 4;
        float acc[4];
        const float bv = b1[col];
#pragma unroll
        for (int r = 0; r < 4; ++r) acc[r] = bv;
#pragma unroll
        for (int k = 0; k < 14; ++k) {
            const float wv = w1[k * 64 + col];
#pragma unroll
            for (int r = 0; r < 4; ++r)
                acc[r] = fmaf(A_[(m0 + r) * SA + k], wv, acc[r]);
        }
#pragma unroll
        for (int r = 0; r < 4; ++r)
            Bb[(m0 + r) * SA + col] = fmaxf(acc[r], 0.f);
    }
    __syncthreads();

    {   // L2: 64 -> 128, relu
        const int col = tid % 128;
        const int m0  = (tid / 128) * 8;
        float acc[8];
        const float bv = b2[col];
#pragma unroll
        for (int r = 0; r < 8; ++r) acc[r] = bv;
#pragma unroll 4
        for (int kq = 0; kq < 16; ++kq) {
            float wv[4];
#pragma unroll
            for (int jj = 0; jj < 4; ++jj) wv[jj] = w2[(4 * kq + jj) * 128 + col];
#pragma unroll
            for (int r = 0; r < 8; ++r) {
                const float4 a4 = *(const float4*)&Bb[(m0 + r) * SA + 4 * kq];
                acc[r] = fmaf(a4.x, wv[0], acc[r]);
                acc[r] = fmaf(a4.y, wv[1], acc[r]);
                acc[r] = fmaf(a4.z, wv[2], acc[r]);
                acc[r] = fmaf(a4.w, wv[3], acc[r]);
            }
        }
#pragma unroll
        for (int r = 0; r < 8; ++r)
            A_[(m0 + r) * SA + col] = fmaxf(acc[r], 0.f);
    }
    __syncthreads();

    {   // L3: 128 -> 256 MFMA
        f32x4 acc[4] = {{0,0,0,0},{0,0,0,0},{0,0,0,0},{0,0,0,0}};
        mfma_acc<128>(wt3, A_, acc, wv_, quad, ln15);
        __syncthreads();
#pragma unroll
        for (int tt = 0; tt < 4; ++tt) {
            const int n = (wv_ * 4 + tt) * 16 + ln15;
            const float bv = b3[n];
#pragma unroll
            for (int r = 0; r < 4; ++r)
                Bb[(quad * 4 + r) * SA + n] = acc[tt][r] + bv;
        }
    }
    __syncthreads();

    {   // L4: 256 -> 256 MFMA, relu
        f32x4 acc[4] = {{0,0,0,0},{0,0,0,0},{0,0,0,0},{0,0,0,0}};
        mfma_acc<256>(wt4, Bb, acc, wv_, quad, ln15);
        __syncthreads();
#pragma unroll
        for (int tt = 0; tt < 4; ++tt) {
            const int n = (wv_ * 4 + tt) * 16 + ln15;
            const float bv = fb1[n];
#pragma unroll
            for (int r = 0; r < 4; ++r)
                A_[(quad * 4 + r) * SA + n] = fmaxf(acc[tt][r] + bv, 0.f);
        }
    }
    __syncthreads();

    {   // L5: 256 -> 256 MFMA -> global
        f32x4 acc[4] = {{0,0,0,0},{0,0,0,0},{0,0,0,0},{0,0,0,0}};
        mfma_acc<256>(wt5, A_, acc, wv_, quad, ln15);
#pragma unroll
        for (int tt = 0; tt < 4; ++tt) {
            const int n = (wv_ * 4 + tt) * 16 + ln15;
            const float bv = fb2[n];
#pragma unroll
            for (int r = 0; r < 4; ++r)
                ft[(size_t)(row0 + quad * 4 + r) * 256 + n] = acc[tt][r] + bv;
        }
    }
}

// ---------------------------------------------------------------------------
// Splat: block = permuted tile (spread heavy tiles across dispatch order);
// 1-barrier chunk pipeline, gws always fully written (0 for padded slots),
// phase B unrolled x4 with independent LDS loads.
// ---------------------------------------------------------------------------
__global__ __launch_bounds__(256)
void splat_kernel(const float* __restrict__ pp, const int* __restrict__ lists,
                  const int* __restrict__ counts, const float* __restrict__ feats,
                  float* __restrict__ out)
{
    __shared__ __align__(16) float feats_s[2][G_ * C_];   // 2 x 16 KB
    __shared__ __align__(16) float gws[2][G_ * 20];       // padded rows

    const int tid = threadIdx.x;
    const int bid = (int)((blockIdx.x * 337u) % NTILES);  // de-clump heavy tiles
    const int txi = bid % NTX;
    const int y   = (bid / NTX) % H_;
    const int b   = bid / (NTX * H_);
    const int x0  = txi * TW;
    const float fy = (float)y;
    const int cnt = min(counts[bid], CAP);
    const int* mylist = lists + (size_t)bid * CAP;
    const int gg  = tid >> 4;
    const int pxi = tid & 15;
    const int cg  = tid >> 2;
    const int pg  = tid & 3;
    const float fx = (float)(x0 + pxi);
    const int bN = b * N_;
    const int lane = tid & 63;
    const int wid  = tid >> 6;

    float acc[16];
#pragma unroll
    for (int t = 0; t < 16; ++t) acc[t] = 0.f;
    float densp = 0.f, uncp = 0.f;

    if (cnt > 0) {
#pragma unroll
        for (int rr = 0; rr < 4; ++rr) {
            const int r = 4 * wid + rr;
            const int n = mylist[min(r, cnt - 1)];
            gl_lds16(feats + (size_t)(bN + n) * C_ + lane * 4,
                     &feats_s[0][r * C_ + lane * 4]);
        }
        const int nchunks = (cnt + G_ - 1) / G_;
        for (int c = 0; c < nchunks; ++c) {
            const int buf = c & 1;
            const int m = min(G_, cnt - c * G_);
            {   // phase A: ALL 16 rows of gws written (0 beyond m)
                const int qi = c * G_ + gg;
                const int n = mylist[min(qi, cnt - 1)];
                const float4 e0 = ((const float4*)pp)[(size_t)(bN + n) * 2 + 0];
                const float4 e1 = ((const float4*)pp)[(size_t)(bN + n) * 2 + 1];
                const float dyn = (fy - e0.y) * e0.w;
                const float dxn = (fx - e0.x) * e0.z;
                const float dist = dyn * dyn + dxn * dxn;
                float gv = 0.f;
                if (dist < 9.f) gv = __expf(-0.5f * dist) * e1.x;
                if (qi >= cnt) gv = 0.f;
                gws[buf][gg * 20 + pxi] = gv;
                densp += gv;
                uncp  += gv * e1.y;
            }
            __syncthreads();              // drains this wave's DMA too
            if (c + 1 < nchunks) {        // DMA c+1, overlaps phase B below
#pragma unroll
                for (int rr = 0; rr < 4; ++rr) {
                    const int r = 4 * wid + rr;
                    const int n = mylist[min((c + 1) * G_ + r, cnt - 1)];
                    gl_lds16(feats + (size_t)(bN + n) * C_ + lane * 4,
                             &feats_s[buf ^ 1][r * C_ + lane * 4]);
                }
            }
            // phase B: unroll x4; padded q's have gw==0 (feats rows are
            // always real finite data via clamped DMA indices).
            const int m4 = (m + 3) & ~3;
            for (int q = 0; q < m4; q += 4) {
                float4 fv[4], gw4[4];
#pragma unroll
                for (int u = 0; u < 4; ++u) {
                    fv[u]  = *(const float4*)&feats_s[buf][(q + u) * C_ + 4 * cg];
                    gw4[u] = *(const float4*)&gws[buf][(q + u) * 20 + 4 * pg];
                }
#pragma unroll
                for (int u = 0; u < 4; ++u) {
                    acc[0]  = fmaf(fv[u].x, gw4[u].x, acc[0]);
                    acc[1]  = fmaf(fv[u].x, gw4[u].y, acc[1]);
                    acc[2]  = fmaf(fv[u].x, gw4[u].z, acc[2]);
                    acc[3]  = fmaf(fv[u].x, gw4[u].w, acc[3]);
                    acc[4]  = fmaf(fv[u].y, gw4[u].x, acc[4]);
                    acc[5]  = fmaf(fv[u].y, gw4[u].y, acc[5]);
                    acc[6]  = fmaf(fv[u].y, gw4[u].z, acc[6]);
                    acc[7]  = fmaf(fv[u].y, gw4[u].w, acc[7]);
                    acc[8]  = fmaf(fv[u].z, gw4[u].x, acc[8]);
                    acc[9]  = fmaf(fv[u].z, gw4[u].y, acc[9]);
                    acc[10] = fmaf(fv[u].z, gw4[u].z, acc[10]);
                    acc[11] = fmaf(fv[u].z, gw4[u].w, acc[11]);
                    acc[12] = fmaf(fv[u].w, gw4[u].x, acc[12]);
                    acc[13] = fmaf(fv[u].w, gw4[u].y, acc[13]);
                    acc[14] = fmaf(fv[u].w, gw4[u].z, acc[14]);
                    acc[15] = fmaf(fv[u].w, gw4[u].w, acc[15]);
                }
            }
        }
    }

    __syncthreads();
    float* red_d = &feats_s[0][0];
    float* red_u = &feats_s[0][512];
    red_d[gg * 20 + pxi] = densp;
    red_u[gg * 20 + pxi] = uncp;
    __syncthreads();
    for (int s = 8; s > 0; s >>= 1) {
        if (gg < s) {
            red_d[gg * 20 + pxi] += red_d[(gg + s) * 20 + pxi];
            red_u[gg * 20 + pxi] += red_u[(gg + s) * 20 + pxi];
        }
        __syncthreads();
    }

    float dclip[4];
#pragma unroll
    for (int jj = 0; jj < 4; ++jj) dclip[jj] = fmaxf(red_d[4 * pg + jj], 1e-6f);

#pragma unroll
    for (int cc = 0; cc < 4; ++cc) {
        const int ch = 4 * cg + cc;
        float4 v;
        v.x = acc[cc * 4 + 0] / dclip[0];
        v.y = acc[cc * 4 + 1] / dclip[1];
        v.z = acc[cc * 4 + 2] / dclip[2];
        v.w = acc[cc * 4 + 3] / dclip[3];
        *(float4*)(out + (((size_t)b * C_ + ch) * H_ + y) * W_ + x0 + 4 * pg) = v;
    }
    if (tid < TW) {
        const size_t pix = ((size_t)b * H_ + y) * W_ + x0 + tid;
        float* unc_o = out + (size_t)B_ * C_ * H_ * W_;
        float* den_o = unc_o + (size_t)B_ * H_ * W_;
        const float d = fmaxf(red_d[tid], 1e-6f);
        unc_o[pix] = red_u[tid] / d;
        den_o[pix] = d;
    }
}

// ---------------------------------------------------------------------------
extern "C" void kernel_launch(void* const* d_in, const int* in_sizes, int n_in,
                              void* d_out, int out_size, void* d_ws, size_t ws_size,
                              hipStream_t stream)
{
    const float* g    = (const float*)d_in[0];
    const float* intr = (const float*)d_in[1];
    const float* w1   = (const float*)d_in[2];
    const float* b1   = (const float*)d_in[3];
    const float* w2   = (const float*)d_in[4];
    const float* b2   = (const float*)d_in[5];
    const float* w3   = (const float*)d_in[6];
    const float* b3   = (const float*)d_in[7];
    const float* fw1  = (const float*)d_in[8];
    const float* fb1  = (const float*)d_in[9];
    const float* fw2  = (const float*)d_in[10];
    const float* fb2  = (const float*)d_in[11];

    char* ws = (char*)d_ws;
    const int rows = B_ * N_;                              // 4096
    float* ft     = (float*)ws;                            // 4 MB
    float* pp     = ft + (size_t)rows * C_;                // 128 KB
    int*   counts = (int*)(pp + (size_t)8 * rows);         // 1408 ints
    int*   lists  = counts + NTILES;                       // 1408*1024 ints (5.8 MB)
    short* wt3    = (short*)(lists + (size_t)NTILES * CAP);// 128*256 bf16
    short* wt4    = wt3 + 128 * 256;                       // 256*256 bf16
    short* wt5    = wt4 + 256 * 256;                       // 256*256 bf16

    hipMemsetAsync(counts, 0, NTILES * sizeof(int), stream);
    parambin_kernel<<<dim3(rows / 8), dim3(256), 0, stream>>>(
        g, intr, w3, fw1, fw2, wt3, wt4, wt5, pp, counts, lists);
    mlp_kernel<<<dim3(rows / 16), dim3(256), 0, stream>>>(
        g, w1, b1, w2, b2, wt3, b3, wt4, fb1, wt5, fb2, ft);
    splat_kernel<<<dim3(NTILES), dim3(256), 0, stream>>>(pp, lists, counts, ft, (float*)d_out);
}

// Round 10
// 190.755 us; speedup vs baseline: 1.0178x; 1.0178x over previous
//
#include <hip/hip_runtime.h>
#include <cstdint>
#include <cstddef>

#define B_ 2
#define N_ 2048
#define C_ 256
#define H_ 64
#define W_ 176
#define TW 16
#define NTX 11                    // 176/16 tiles per row
#define NTILES (B_*H_*NTX)        // 1408
#define CAP 1024                  // per-tile list cap
#define G2 32                     // gaussians per splat chunk
#define SA 260                    // mlp act LDS stride (floats)

typedef unsigned short ushort_t;
typedef short bf16x8 __attribute__((ext_vector_type(8)));
typedef float f32x4  __attribute__((ext_vector_type(4)));

__device__ __forceinline__ short f2bf(float f)   // RNE fp32->bf16
{
    unsigned u = __float_as_uint(f);
    return (short)((u + 0x7FFFu + ((u >> 16) & 1u)) >> 16);
}

// global->LDS direct DMA: each lane moves 16B; dest = uniform base + lane*16.
__device__ __forceinline__ void gl_lds16u(const ushort_t* gsrc, ushort_t* ldst)
{
    auto gp = (const __attribute__((address_space(1))) unsigned int*)(uintptr_t)gsrc;
    auto lp = (__attribute__((address_space(3))) unsigned int*)(unsigned int)(uintptr_t)ldst;
    __builtin_amdgcn_global_load_lds(gp, lp, 16, 0, 0);
}

// ---------------------------------------------------------------------------
// Fused param + bin + weight-convert (unchanged from R8).
// ---------------------------------------------------------------------------
__global__ __launch_bounds__(256)
void parambin_kernel(const float* __restrict__ g, const float* __restrict__ intr,
                     const float* __restrict__ w3f, const float* __restrict__ fw1f,
                     const float* __restrict__ fw2f,
                     short* __restrict__ wt3, short* __restrict__ wt4,
                     short* __restrict__ wt5,
                     float* __restrict__ pp, int* __restrict__ counts,
                     int* __restrict__ lists)
{
    const int tid = threadIdx.x;
    const int gid = blockIdx.x * 256 + tid;
    for (int e = gid; e < 163840; e += 131072) {
        if (e < 32768) {
            const int k = e >> 8, n = e & 255;
            wt3[n * 128 + k] = f2bf(w3f[e]);
        } else if (e < 98304) {
            const int i = e - 32768, k = i >> 8, n = i & 255;
            wt4[n * 256 + k] = f2bf(fw1f[i]);
        } else {
            const int i = e - 98304, k = i >> 8, n = i & 255;
            wt5[n * 256 + k] = f2bf(fw2f[i]);
        }
    }
    const int i = blockIdx.x * 8 + (tid >> 5);
    const int j = tid & 31;
    const float* gi = g + (size_t)i * 14;
    const float x = gi[0], y = gi[1], z = gi[2];
    const float s5 = gi[5], s6 = gi[6], wv = gi[12];
    const float k00 = intr[0], k01 = intr[1], k02 = intr[2];
    const float k10 = intr[3], k11 = intr[4], k12 = intr[5];
    const float k20 = intr[6], k21 = intr[7], k22 = intr[8];
    const float projx = k00 * x + k01 * y + k02 * z;
    const float projy = k10 * x + k11 * y + k12 * z;
    const float projz = k20 * x + k21 * y + k22 * z;
    const float inv = 1.f / (projz + 1e-6f);
    const float scale_x = (float)W_ / k02 * 0.5f;
    const float scale_y = (float)H_ / k12 * 0.5f;
    const float px = projx * inv * scale_x;
    const float py = projy * inv * scale_y;
    const bool valid = z > 0.1f;
    const bool inb = (px >= 0.f) && (px < (float)W_) && (py >= 0.f) && (py < (float)H_);
    const bool mask = valid && inb;
    const float sx = fmaxf(s5 * scale_x, 1.f);
    const float sy = fmaxf(s6 * scale_y, 1.f);
    if (j == 0) {
        float4* o = (float4*)(pp + (size_t)i * 8);
        o[0] = make_float4(px, py, 1.f / sx, 1.f / sy);
        o[1] = make_float4(wv, 0.5f * (sx + sy), 0.f, 0.f);
    }
    if (!mask) return;
    const float rx = 3.f * sx, ry = 3.f * sy;
    const int ymin = max(0, (int)floorf(py - ry));
    const int ymax = min(H_ - 1, (int)ceilf(py + ry));
    const int yy = ymin + j;
    if (yy > ymax) return;
    const int tmin = max(0, (int)floorf((px - rx - (float)(TW - 1)) * (1.f / TW)));
    const int tmax = min(NTX - 1, (int)ceilf((px + rx) * (1.f / TW)));
    const int b = i / N_, n = i - b * N_;
    for (int t = tmin; t <= tmax; ++t) {
        const int tile = (b * H_ + yy) * NTX + t;
        const int slot = atomicAdd(&counts[tile], 1);
        if (slot < CAP) lists[(size_t)tile * CAP + slot] = n;
    }
}

// ---------------------------------------------------------------------------
// MFMA helper (unchanged from R8).
// ---------------------------------------------------------------------------
template<int K>
__device__ __forceinline__ void mfma_acc(const short* __restrict__ wt,
                                         const float* actIn, f32x4 (&acc)[4],
                                         int wv_, int quad, int ln15)
{
#pragma unroll
    for (int ks = 0; ks < K / 32; ++ks) {
        const int kb = ks * 32 + quad * 8;
        const float4 a0 = *(const float4*)&actIn[ln15 * SA + kb];
        const float4 a1 = *(const float4*)&actIn[ln15 * SA + kb + 4];
        bf16x8 af = { f2bf(a0.x), f2bf(a0.y), f2bf(a0.z), f2bf(a0.w),
                      f2bf(a1.x), f2bf(a1.y), f2bf(a1.z), f2bf(a1.w) };
#pragma unroll
        for (int tt = 0; tt < 4; ++tt) {
            const int n0 = (wv_ * 4 + tt) * 16;
            const bf16x8 bf = *(const bf16x8*)&wt[(size_t)(n0 + ln15) * K + kb];
            acc[tt] = __builtin_amdgcn_mfma_f32_16x16x32_bf16(af, bf, acc[tt], 0, 0, 0);
        }
    }
}

// ---------------------------------------------------------------------------
// Fused MLP (R8 structure); L5 epilogue now writes ft in bf16 [n][ch].
// ---------------------------------------------------------------------------
__global__ __launch_bounds__(256)
void mlp_kernel(const float* __restrict__ g,
                const float* __restrict__ w1, const float* __restrict__ b1,
                const float* __restrict__ w2, const float* __restrict__ b2,
                const short* __restrict__ wt3, const float* __restrict__ b3,
                const short* __restrict__ wt4, const float* __restrict__ fb1,
                const short* __restrict__ wt5, const float* __restrict__ fb2,
                ushort_t* __restrict__ ftb)
{
    __shared__ __align__(16) float A_[16 * SA];
    __shared__ __align__(16) float Bb[16 * SA];
    const int tid  = threadIdx.x;
    const int row0 = blockIdx.x * 16;
    const int lane = tid & 63;
    const int wv_  = tid >> 6;
    const int quad = lane >> 4;
    const int ln15 = lane & 15;

    if (tid < 224) {
        const int k = tid / 16, m = tid % 16;
        A_[m * SA + k] = g[(size_t)(row0 + m) * 14 + k];
    }
    __syncthreads();

    {   // L1: 14 -> 64, relu
        const int col = tid & 63;
        const int m0  = (tid >> 6) * 4;
        float acc[4];
        const float bv = b1[col];
#pragma unroll
        for (int r = 0; r < 4; ++r) acc[r] = bv;
#pragma unroll
        for (int k = 0; k < 14; ++k) {
            const float wv = w1[k * 64 + col];
#pragma unroll
            for (int r = 0; r < 4; ++r)
                acc[r] = fmaf(A_[(m0 + r) * SA + k], wv, acc[r]);
        }
#pragma unroll
        for (int r = 0; r < 4; ++r)
            Bb[(m0 + r) * SA + col] = fmaxf(acc[r], 0.f);
    }
    __syncthreads();

    {   // L2: 64 -> 128, relu
        const int col = tid % 128;
        const int m0  = (tid / 128) * 8;
        float acc[8];
        const float bv = b2[col];
#pragma unroll
        for (int r = 0; r < 8; ++r) acc[r] = bv;
#pragma unroll 4
        for (int kq = 0; kq < 16; ++kq) {
            float wv[4];
#pragma unroll
            for (int jj = 0; jj < 4; ++jj) wv[jj] = w2[(4 * kq + jj) * 128 + col];
#pragma unroll
            for (int r = 0; r < 8; ++r) {
                const float4 a4 = *(const float4*)&Bb[(m0 + r) * SA + 4 * kq];
                acc[r] = fmaf(a4.x, wv[0], acc[r]);
                acc[r] = fmaf(a4.y, wv[1], acc[r]);
                acc[r] = fmaf(a4.z, wv[2], acc[r]);
                acc[r] = fmaf(a4.w, wv[3], acc[r]);
            }
        }
#pragma unroll
        for (int r = 0; r < 8; ++r)
            A_[(m0 + r) * SA + col] = fmaxf(acc[r], 0.f);
    }
    __syncthreads();

    {   // L3: 128 -> 256 MFMA
        f32x4 acc[4] = {{0,0,0,0},{0,0,0,0},{0,0,0,0},{0,0,0,0}};
        mfma_acc<128>(wt3, A_, acc, wv_, quad, ln15);
        __syncthreads();
#pragma unroll
        for (int tt = 0; tt < 4; ++tt) {
            const int n = (wv_ * 4 + tt) * 16 + ln15;
            const float bv = b3[n];
#pragma unroll
            for (int r = 0; r < 4; ++r)
                Bb[(quad * 4 + r) * SA + n] = acc[tt][r] + bv;
        }
    }
    __syncthreads();

    {   // L4: 256 -> 256 MFMA, relu
        f32x4 acc[4] = {{0,0,0,0},{0,0,0,0},{0,0,0,0},{0,0,0,0}};
        mfma_acc<256>(wt4, Bb, acc, wv_, quad, ln15);
        __syncthreads();
#pragma unroll
        for (int tt = 0; tt < 4; ++tt) {
            const int n = (wv_ * 4 + tt) * 16 + ln15;
            const float bv = fb1[n];
#pragma unroll
            for (int r = 0; r < 4; ++r)
                A_[(quad * 4 + r) * SA + n] = fmaxf(acc[tt][r] + bv, 0.f);
        }
    }
    __syncthreads();

    {   // L5: 256 -> 256 MFMA -> global bf16
        f32x4 acc[4] = {{0,0,0,0},{0,0,0,0},{0,0,0,0},{0,0,0,0}};
        mfma_acc<256>(wt5, A_, acc, wv_, quad, ln15);
#pragma unroll
        for (int tt = 0; tt < 4; ++tt) {
            const int n = (wv_ * 4 + tt) * 16 + ln15;
            const float bv = fb2[n];
#pragma unroll
            for (int r = 0; r < 4; ++r)
                ftb[(size_t)(row0 + quad * 4 + r) * 256 + n] =
                    (ushort_t)f2bf(acc[tt][r] + bv);
        }
    }
}

// ---------------------------------------------------------------------------
// Splat: block = tile (sequential bids for L2 locality); G2=32 chunks.
// Phase A: thread (gg,pxi) computes gw for q=gg and q=gg+16 (idx prefetched).
// Feats staged bf16 via global_load_lds (2 rows per instr, idx via shfl).
// Phase B: 8ch x 4px tile, 2-way q-split; acc merged once per tile.
// ---------------------------------------------------------------------------
__global__ __launch_bounds__(256)
void splat_kernel(const float* __restrict__ pp, const int* __restrict__ lists,
                  const int* __restrict__ counts, const ushort_t* __restrict__ feats,
                  float* __restrict__ out)
{
    __shared__ __align__(16) ushort_t feats_bf[2][G2 * C_];  // 2 x 16 KB
    __shared__ __align__(16) float gws[2][G2 * 20];          // 2 x 2.5 KB

    const int tid = threadIdx.x;
    const int bid = blockIdx.x;
    const int txi = bid % NTX;
    const int y   = (bid / NTX) % H_;
    const int b   = bid / (NTX * H_);
    const int x0  = txi * TW;
    const float fy = (float)y;
    const int cnt = min(counts[bid], CAP);
    const int* mylist = lists + (size_t)bid * CAP;
    const int gg  = tid >> 4;             // phase A gaussian slot (0..15)
    const int pxi = tid & 15;
    const int pos = tid & 127;            // phase B position
    const int qo  = tid >> 7;             // phase B q parity
    const int cho = pos >> 2;             // ch octet (0..31)
    const int pg  = pos & 3;              // px quad
    const float fx = (float)(x0 + pxi);
    const int bN = b * N_;
    const int lane = tid & 63;
    const int wid  = tid >> 6;

    float acc[8][4];
#pragma unroll
    for (int cc = 0; cc < 8; ++cc)
#pragma unroll
        for (int k = 0; k < 4; ++k) acc[cc][k] = 0.f;
    float densp = 0.f, uncp = 0.f;

    if (cnt > 0) {
        int idxA = mylist[min(gg, cnt - 1)];
        int idxB = mylist[min(gg + 16, cnt - 1)];
        // prologue DMA chunk 0: wave wid stages rows {4w..4w+3, 4w+16..4w+19}
#pragma unroll
        for (int j = 0; j < 2; ++j) {
            {
                const int nLo = __shfl(idxA, 32 * j);
                const int nHi = __shfl(idxA, 32 * j + 16);
                const int n = (lane < 32) ? nLo : nHi;
                gl_lds16u(feats + ((size_t)(bN + n) << 8) + (lane & 31) * 8,
                          &feats_bf[0][(4 * wid + 2 * j) * 256] + lane * 8);
            }
            {
                const int nLo = __shfl(idxB, 32 * j);
                const int nHi = __shfl(idxB, 32 * j + 16);
                const int n = (lane < 32) ? nLo : nHi;
                gl_lds16u(feats + ((size_t)(bN + n) << 8) + (lane & 31) * 8,
                          &feats_bf[0][(4 * wid + 16 + 2 * j) * 256] + lane * 8);
            }
        }
        const int nchunks = (cnt + G2 - 1) / G2;
        const float4* pv = (const float4*)pp;
        for (int c = 0; c < nchunks; ++c) {
            const int buf = c & 1;
            // prefetch next chunk's indices (hidden under phase A)
            const int idxAn = mylist[min((c + 1) * G2 + gg, cnt - 1)];
            const int idxBn = mylist[min((c + 1) * G2 + gg + 16, cnt - 1)];
            // phase A: two gaussians per thread
            {
                const int qi = c * G2 + gg;
                const float4 e0 = pv[(size_t)(bN + idxA) * 2 + 0];
                const float4 e1 = pv[(size_t)(bN + idxA) * 2 + 1];
                const float dyn = (fy - e0.y) * e0.w;
                const float dxn = (fx - e0.x) * e0.z;
                const float dist = dyn * dyn + dxn * dxn;
                float gv = 0.f;
                if (dist < 9.f) gv = __expf(-0.5f * dist) * e1.x;
                if (qi >= cnt) gv = 0.f;
                gws[buf][gg * 20 + pxi] = gv;
                densp += gv;
                uncp  += gv * e1.y;

                const float4 f0 = pv[(size_t)(bN + idxB) * 2 + 0];
                const float4 f1 = pv[(size_t)(bN + idxB) * 2 + 1];
                const float dyn2 = (fy - f0.y) * f0.w;
                const float dxn2 = (fx - f0.x) * f0.z;
                const float dist2 = dyn2 * dyn2 + dxn2 * dxn2;
                float gv2 = 0.f;
                if (dist2 < 9.f) gv2 = __expf(-0.5f * dist2) * f1.x;
                if (qi + 16 >= cnt) gv2 = 0.f;
                gws[buf][(gg + 16) * 20 + pxi] = gv2;
                densp += gv2;
                uncp  += gv2 * f1.y;
            }
            __syncthreads();   // gws[buf] ready; this wave's DMA(c) drained
            if (c + 1 < nchunks) {  // DMA chunk c+1 into buf^1 (overlaps phase B)
#pragma unroll
                for (int j = 0; j < 2; ++j) {
                    {
                        const int nLo = __shfl(idxAn, 32 * j);
                        const int nHi = __shfl(idxAn, 32 * j + 16);
                        const int n = (lane < 32) ? nLo : nHi;
                        gl_lds16u(feats + ((size_t)(bN + n) << 8) + (lane & 31) * 8,
                                  &feats_bf[buf ^ 1][(4 * wid + 2 * j) * 256] + lane * 8);
                    }
                    {
                        const int nLo = __shfl(idxBn, 32 * j);
                        const int nHi = __shfl(idxBn, 32 * j + 16);
                        const int n = (lane < 32) ? nLo : nHi;
                        gl_lds16u(feats + ((size_t)(bN + n) << 8) + (lane & 31) * 8,
                                  &feats_bf[buf ^ 1][(4 * wid + 16 + 2 * j) * 256] + lane * 8);
                    }
                }
            }
            // phase B: 16 q-pair iterations; thread handles q = 2*it + qo
#pragma unroll 4
            for (int it = 0; it < 16; ++it) {
                const int q = 2 * it + qo;
                const uint4 fw = *(const uint4*)&feats_bf[buf][q * 256 + cho * 8];
                const float4 g4 = *(const float4*)&gws[buf][q * 20 + 4 * pg];
                float fch[8];
                fch[0] = __uint_as_float(fw.x << 16);
                fch[1] = __uint_as_float(fw.x & 0xffff0000u);
                fch[2] = __uint_as_float(fw.y << 16);
                fch[3] = __uint_as_float(fw.y & 0xffff0000u);
                fch[4] = __uint_as_float(fw.z << 16);
                fch[5] = __uint_as_float(fw.z & 0xffff0000u);
                fch[6] = __uint_as_float(fw.w << 16);
                fch[7] = __uint_as_float(fw.w & 0xffff0000u);
#pragma unroll
                for (int cc = 0; cc < 8; ++cc) {
                    acc[cc][0] = fmaf(fch[cc], g4.x, acc[cc][0]);
                    acc[cc][1] = fmaf(fch[cc], g4.y, acc[cc][1]);
                    acc[cc][2] = fmaf(fch[cc], g4.z, acc[cc][2]);
                    acc[cc][3] = fmaf(fch[cc], g4.w, acc[cc][3]);
                }
            }
            idxA = idxAn;
            idxB = idxBn;
        }
    }

    // density / uncertainty reduction (scratch in feats_bf[0] region)
    __syncthreads();
    float* red_d = (float*)&feats_bf[0][0];   // 16 x 20
    float* red_u = red_d + 512;
    red_d[gg * 20 + pxi] = densp;
    red_u[gg * 20 + pxi] = uncp;
    __syncthreads();
    for (int s = 8; s > 0; s >>= 1) {
        if (gg < s) {
            red_d[gg * 20 + pxi] += red_d[(gg + s) * 20 + pxi];
            red_u[gg * 20 + pxi] += red_u[(gg + s) * 20 + pxi];
        }
        __syncthreads();
    }

    // read dclip + write unc/dens BEFORE clobbering red area with merge buffer
    float rinv[4];
#pragma unroll
    for (int k = 0; k < 4; ++k) rinv[k] = 1.f / fmaxf(red_d[4 * pg + k], 1e-6f);
    if (tid < TW) {
        const size_t pix = ((size_t)b * H_ + y) * W_ + x0 + tid;
        float* unc_o = out + (size_t)B_ * C_ * H_ * W_;
        float* den_o = unc_o + (size_t)B_ * H_ * W_;
        const float d = fmaxf(red_d[tid], 1e-6f);
        unc_o[pix] = red_u[tid] / d;
        den_o[pix] = d;
    }
    __syncthreads();

    // merge the two q-parity acc copies: qo==1 stages, qo==0 adds + stores
    float4* mb = (float4*)&feats_bf[0][0];    // 8 x 128 float4 = 16 KB
    if (qo == 1) {
#pragma unroll
        for (int cc = 0; cc < 8; ++cc)
            mb[cc * 128 + pos] = make_float4(acc[cc][0], acc[cc][1],
                                             acc[cc][2], acc[cc][3]);
    }
    __syncthreads();
    if (qo == 0) {
#pragma unroll
        for (int cc = 0; cc < 8; ++cc) {
            const float4 o = mb[cc * 128 + pos];
            float4 v;
            v.x = (acc[cc][0] + o.x) * rinv[0];
            v.y = (acc[cc][1] + o.y) * rinv[1];
            v.z = (acc[cc][2] + o.z) * rinv[2];
            v.w = (acc[cc][3] + o.w) * rinv[3];
            const int ch = cho * 8 + cc;
            *(float4*)(out + (((size_t)b * C_ + ch) * H_ + y) * W_ + x0 + 4 * pg) = v;
        }
    }
}

// ---------------------------------------------------------------------------
extern "C" void kernel_launch(void* const* d_in, const int* in_sizes, int n_in,
                              void* d_out, int out_size, void* d_ws, size_t ws_size,
                              hipStream_t stream)
{
    const float* g    = (const float*)d_in[0];
    const float* intr = (const float*)d_in[1];
    const float* w1   = (const float*)d_in[2];
    const float* b1   = (const float*)d_in[3];
    const float* w2   = (const float*)d_in[4];
    const float* b2   = (const float*)d_in[5];
    const float* w3   = (const float*)d_in[6];
    const float* b3   = (const float*)d_in[7];
    const float* fw1  = (const float*)d_in[8];
    const float* fb1  = (const float*)d_in[9];
    const float* fw2  = (const float*)d_in[10];
    const float* fb2  = (const float*)d_in[11];

    char* base = (char*)d_ws;
    const int rows = B_ * N_;                               // 4096
    ushort_t* ftb = (ushort_t*)base;                        // 2 MB bf16 [n][ch]
    float* pp     = (float*)(base + (size_t)rows * C_ * 2); // 128 KB
    int*   counts = (int*)(pp + (size_t)8 * rows);          // 1408 ints
    int*   lists  = counts + NTILES;                        // 1408*1024 ints
    short* wt3    = (short*)(lists + (size_t)NTILES * CAP); // 128*256 bf16
    short* wt4    = wt3 + 128 * 256;                        // 256*256 bf16
    short* wt5    = wt4 + 256 * 256;                        // 256*256 bf16

    hipMemsetAsync(counts, 0, NTILES * sizeof(int), stream);
    parambin_kernel<<<dim3(rows / 8), dim3(256), 0, stream>>>(
        g, intr, w3, fw1, fw2, wt3, wt4, wt5, pp, counts, lists);
    mlp_kernel<<<dim3(rows / 16), dim3(256), 0, stream>>>(
        g, w1, b1, w2, b2, wt3, b3, wt4, fb1, wt5, fb2, ftb);
    splat_kernel<<<dim3(NTILES), dim3(256), 0, stream>>>(pp, lists, counts, ftb, (float*)d_out);
}

// Round 11
// 181.008 us; speedup vs baseline: 1.0727x; 1.0538x over previous
//
#include <hip/hip_runtime.h>
#include <cstdint>
#include <cstddef>

#define B_ 2
#define N_ 2048
#define C_ 256
#define H_ 64
#define W_ 176
#define TW 16
#define NTX 11                    // 176/16 tiles per row
#define NTILES (B_*H_*NTX)        // 1408
#define CAP 1024                  // per-tile list cap
#define G2 32                     // gaussians per splat chunk
#define SA 260                    // mlp act LDS stride (floats)

typedef unsigned short ushort_t;
typedef short bf16x8 __attribute__((ext_vector_type(8)));
typedef float f32x4  __attribute__((ext_vector_type(4)));

__device__ __forceinline__ short f2bf(float f)   // RNE fp32->bf16
{
    unsigned u = __float_as_uint(f);
    return (short)((u + 0x7FFFu + ((u >> 16) & 1u)) >> 16);
}

// global->LDS direct DMA: each lane moves 16B; dest = uniform base + lane*16.
__device__ __forceinline__ void gl_lds16u(const ushort_t* gsrc, ushort_t* ldst)
{
    auto gp = (const __attribute__((address_space(1))) unsigned int*)(uintptr_t)gsrc;
    auto lp = (__attribute__((address_space(3))) unsigned int*)(unsigned int)(uintptr_t)ldst;
    __builtin_amdgcn_global_load_lds(gp, lp, 16, 0, 0);
}

// ---------------------------------------------------------------------------
// prep: zero tile counters + fp32->bf16 transposed weight convert with
// COALESCED writes (wt[i] contiguous per thread; transposed read from L2).
// grid 256 x 256.
// ---------------------------------------------------------------------------
__global__ __launch_bounds__(256)
void prep_kernel(const float* __restrict__ w3f, const float* __restrict__ fw1f,
                 const float* __restrict__ fw2f,
                 short* __restrict__ wt3, short* __restrict__ wt4,
                 short* __restrict__ wt5, int* __restrict__ counts)
{
    const int gid = blockIdx.x * 256 + threadIdx.x;
    if (gid < NTILES) counts[gid] = 0;
    for (int e = gid; e < 163840; e += 65536) {
        if (e < 32768) {
            const int i = e;                    // wt3[n*128+k] == wt3[i]
            wt3[i] = f2bf(w3f[(i & 127) * 256 + (i >> 7)]);
        } else if (e < 98304) {
            const int i = e - 32768;
            wt4[i] = f2bf(fw1f[(i & 255) * 256 + (i >> 8)]);
        } else {
            const int i = e - 98304;
            wt5[i] = f2bf(fw2f[(i & 255) * 256 + (i >> 8)]);
        }
    }
}

// ---------------------------------------------------------------------------
// MFMA helper (R8-verified).
// ---------------------------------------------------------------------------
template<int K>
__device__ __forceinline__ void mfma_acc(const short* __restrict__ wt,
                                         const float* actIn, f32x4 (&acc)[4],
                                         int wv_, int quad, int ln15)
{
#pragma unroll
    for (int ks = 0; ks < K / 32; ++ks) {
        const int kb = ks * 32 + quad * 8;
        const float4 a0 = *(const float4*)&actIn[ln15 * SA + kb];
        const float4 a1 = *(const float4*)&actIn[ln15 * SA + kb + 4];
        bf16x8 af = { f2bf(a0.x), f2bf(a0.y), f2bf(a0.z), f2bf(a0.w),
                      f2bf(a1.x), f2bf(a1.y), f2bf(a1.z), f2bf(a1.w) };
#pragma unroll
        for (int tt = 0; tt < 4; ++tt) {
            const int n0 = (wv_ * 4 + tt) * 16;
            const bf16x8 bf = *(const bf16x8*)&wt[(size_t)(n0 + ln15) * K + kb];
            acc[tt] = __builtin_amdgcn_mfma_f32_16x16x32_bf16(af, bf, acc[tt], 0, 0, 0);
        }
    }
}

// ---------------------------------------------------------------------------
// Fused MLP + param/bin in one dispatch (independent work, concurrent):
//   blocks 0..255   : MLP, 16 rows each (R10 body, bf16 ft output)
//   blocks 256..767 : param+bin, 8 gaussians x 32 y-rows each
// ---------------------------------------------------------------------------
__global__ __launch_bounds__(256)
void pb_mlp_kernel(const float* __restrict__ g, const float* __restrict__ intr,
                   const float* __restrict__ w1, const float* __restrict__ b1,
                   const float* __restrict__ w2, const float* __restrict__ b2,
                   const short* __restrict__ wt3, const float* __restrict__ b3,
                   const short* __restrict__ wt4, const float* __restrict__ fb1,
                   const short* __restrict__ wt5, const float* __restrict__ fb2,
                   ushort_t* __restrict__ ftb,
                   float* __restrict__ pp, int* __restrict__ counts,
                   int* __restrict__ lists)
{
    __shared__ __align__(16) float A_[16 * SA];
    __shared__ __align__(16) float Bb[16 * SA];
    const int tid = threadIdx.x;

    if (blockIdx.x < 256) {
        // ================= MLP role =================
        const int row0 = blockIdx.x * 16;
        const int lane = tid & 63;
        const int wv_  = tid >> 6;
        const int quad = lane >> 4;
        const int ln15 = lane & 15;

        if (tid < 224) {
            const int k = tid / 16, m = tid % 16;
            A_[m * SA + k] = g[(size_t)(row0 + m) * 14 + k];
        }
        __syncthreads();

        {   // L1: 14 -> 64, relu
            const int col = tid & 63;
            const int m0  = (tid >> 6) * 4;
            float acc[4];
            const float bv = b1[col];
#pragma unroll
            for (int r = 0; r < 4; ++r) acc[r] = bv;
#pragma unroll
            for (int k = 0; k < 14; ++k) {
                const float wv = w1[k * 64 + col];
#pragma unroll
                for (int r = 0; r < 4; ++r)
                    acc[r] = fmaf(A_[(m0 + r) * SA + k], wv, acc[r]);
            }
#pragma unroll
            for (int r = 0; r < 4; ++r)
                Bb[(m0 + r) * SA + col] = fmaxf(acc[r], 0.f);
        }
        __syncthreads();

        {   // L2: 64 -> 128, relu
            const int col = tid % 128;
            const int m0  = (tid / 128) * 8;
            float acc[8];
            const float bv = b2[col];
#pragma unroll
            for (int r = 0; r < 8; ++r) acc[r] = bv;
#pragma unroll 4
            for (int kq = 0; kq < 16; ++kq) {
                float wv[4];
#pragma unroll
                for (int jj = 0; jj < 4; ++jj) wv[jj] = w2[(4 * kq + jj) * 128 + col];
#pragma unroll
                for (int r = 0; r < 8; ++r) {
                    const float4 a4 = *(const float4*)&Bb[(m0 + r) * SA + 4 * kq];
                    acc[r] = fmaf(a4.x, wv[0], acc[r]);
                    acc[r] = fmaf(a4.y, wv[1], acc[r]);
                    acc[r] = fmaf(a4.z, wv[2], acc[r]);
                    acc[r] = fmaf(a4.w, wv[3], acc[r]);
                }
            }
#pragma unroll
            for (int r = 0; r < 8; ++r)
                A_[(m0 + r) * SA + col] = fmaxf(acc[r], 0.f);
        }
        __syncthreads();

        {   // L3: 128 -> 256 MFMA
            f32x4 acc[4] = {{0,0,0,0},{0,0,0,0},{0,0,0,0},{0,0,0,0}};
            mfma_acc<128>(wt3, A_, acc, wv_, quad, ln15);
            __syncthreads();
#pragma unroll
            for (int tt = 0; tt < 4; ++tt) {
                const int n = (wv_ * 4 + tt) * 16 + ln15;
                const float bv = b3[n];
#pragma unroll
                for (int r = 0; r < 4; ++r)
                    Bb[(quad * 4 + r) * SA + n] = acc[tt][r] + bv;
            }
        }
        __syncthreads();

        {   // L4: 256 -> 256 MFMA, relu
            f32x4 acc[4] = {{0,0,0,0},{0,0,0,0},{0,0,0,0},{0,0,0,0}};
            mfma_acc<256>(wt4, Bb, acc, wv_, quad, ln15);
            __syncthreads();
#pragma unroll
            for (int tt = 0; tt < 4; ++tt) {
                const int n = (wv_ * 4 + tt) * 16 + ln15;
                const float bv = fb1[n];
#pragma unroll
                for (int r = 0; r < 4; ++r)
                    A_[(quad * 4 + r) * SA + n] = fmaxf(acc[tt][r] + bv, 0.f);
            }
        }
        __syncthreads();

        {   // L5: 256 -> 256 MFMA -> global bf16
            f32x4 acc[4] = {{0,0,0,0},{0,0,0,0},{0,0,0,0},{0,0,0,0}};
            mfma_acc<256>(wt5, A_, acc, wv_, quad, ln15);
#pragma unroll
            for (int tt = 0; tt < 4; ++tt) {
                const int n = (wv_ * 4 + tt) * 16 + ln15;
                const float bv = fb2[n];
#pragma unroll
                for (int r = 0; r < 4; ++r)
                    ftb[(size_t)(row0 + quad * 4 + r) * 256 + n] =
                        (ushort_t)f2bf(acc[tt][r] + bv);
            }
        }
        return;
    }

    // ================= param + bin role =================
    const int i = (blockIdx.x - 256) * 8 + (tid >> 5);
    const int j = tid & 31;
    const float* gi = g + (size_t)i * 14;
    const float x = gi[0], y = gi[1], z = gi[2];
    const float s5 = gi[5], s6 = gi[6], wv = gi[12];
    const float k00 = intr[0], k01 = intr[1], k02 = intr[2];
    const float k10 = intr[3], k11 = intr[4], k12 = intr[5];
    const float k20 = intr[6], k21 = intr[7], k22 = intr[8];
    const float projx = k00 * x + k01 * y + k02 * z;
    const float projy = k10 * x + k11 * y + k12 * z;
    const float projz = k20 * x + k21 * y + k22 * z;
    const float inv = 1.f / (projz + 1e-6f);
    const float scale_x = (float)W_ / k02 * 0.5f;
    const float scale_y = (float)H_ / k12 * 0.5f;
    const float px = projx * inv * scale_x;
    const float py = projy * inv * scale_y;
    const bool valid = z > 0.1f;
    const bool inb = (px >= 0.f) && (px < (float)W_) && (py >= 0.f) && (py < (float)H_);
    const bool mask = valid && inb;
    const float sx = fmaxf(s5 * scale_x, 1.f);
    const float sy = fmaxf(s6 * scale_y, 1.f);
    if (j == 0) {
        float4* o = (float4*)(pp + (size_t)i * 8);
        o[0] = make_float4(px, py, 1.f / sx, 1.f / sy);
        o[1] = make_float4(wv, 0.5f * (sx + sy), 0.f, 0.f);
    }
    if (!mask) return;
    const float rx = 3.f * sx, ry = 3.f * sy;
    const int ymin = max(0, (int)floorf(py - ry));
    const int ymax = min(H_ - 1, (int)ceilf(py + ry));
    const int yy = ymin + j;
    if (yy > ymax) return;
    const int tmin = max(0, (int)floorf((px - rx - (float)(TW - 1)) * (1.f / TW)));
    const int tmax = min(NTX - 1, (int)ceilf((px + rx) * (1.f / TW)));
    const int b = i / N_, n = i - b * N_;
    for (int t = tmin; t <= tmax; ++t) {
        const int tile = (b * H_ + yy) * NTX + t;
        const int slot = atomicAdd(&counts[tile], 1);
        if (slot < CAP) lists[(size_t)tile * CAP + slot] = n;
    }
}

// ---------------------------------------------------------------------------
// Splat (R10 body): center-first dispatch order (heavy tiles start first,
// adjacent dispatches are neighboring rows -> L2 locality preserved).
// ---------------------------------------------------------------------------
__global__ __launch_bounds__(256)
void splat_kernel(const float* __restrict__ pp, const int* __restrict__ lists,
                  const int* __restrict__ counts, const ushort_t* __restrict__ feats,
                  float* __restrict__ out)
{
    __shared__ __align__(16) ushort_t feats_bf[2][G2 * C_];  // 2 x 16 KB
    __shared__ __align__(16) float gws[2][G2 * 20];          // 2 x 2.5 KB

    const int tid = threadIdx.x;
    // center-first tile mapping
    const int q  = blockIdx.x;
    const int b  = q & 1;
    const int t_ = q >> 1;
    const int yr = t_ / NTX, xr = t_ % NTX;
    const int yh = (yr + 1) >> 1;
    const int y  = (yr & 1) ? (32 - yh) : (32 + yh);
    const int xh = (xr + 1) >> 1;
    const int txi = (xr & 1) ? (5 - xh) : (5 + xh);
    const int bid = (b * H_ + y) * NTX + txi;

    const int x0  = txi * TW;
    const float fy = (float)y;
    const int cnt = min(counts[bid], CAP);
    const int* mylist = lists + (size_t)bid * CAP;
    const int gg  = tid >> 4;             // phase A gaussian slot (0..15)
    const int pxi = tid & 15;
    const int pos = tid & 127;            // phase B position
    const int qo  = tid >> 7;             // phase B q parity
    const int cho = pos >> 2;             // ch octet (0..31)
    const int pg  = pos & 3;              // px quad
    const float fx = (float)(x0 + pxi);
    const int bN = b * N_;
    const int lane = tid & 63;
    const int wid  = tid >> 6;

    float acc[8][4];
#pragma unroll
    for (int cc = 0; cc < 8; ++cc)
#pragma unroll
        for (int k = 0; k < 4; ++k) acc[cc][k] = 0.f;
    float densp = 0.f, uncp = 0.f;

    if (cnt > 0) {
        int idxA = mylist[min(gg, cnt - 1)];
        int idxB = mylist[min(gg + 16, cnt - 1)];
#pragma unroll
        for (int j = 0; j < 2; ++j) {
            {
                const int nLo = __shfl(idxA, 32 * j);
                const int nHi = __shfl(idxA, 32 * j + 16);
                const int n = (lane < 32) ? nLo : nHi;
                gl_lds16u(feats + ((size_t)(bN + n) << 8) + (lane & 31) * 8,
                          &feats_bf[0][(4 * wid + 2 * j) * 256] + lane * 8);
            }
            {
                const int nLo = __shfl(idxB, 32 * j);
                const int nHi = __shfl(idxB, 32 * j + 16);
                const int n = (lane < 32) ? nLo : nHi;
                gl_lds16u(feats + ((size_t)(bN + n) << 8) + (lane & 31) * 8,
                          &feats_bf[0][(4 * wid + 16 + 2 * j) * 256] + lane * 8);
            }
        }
        const int nchunks = (cnt + G2 - 1) / G2;
        const float4* pv = (const float4*)pp;
        for (int c = 0; c < nchunks; ++c) {
            const int buf = c & 1;
            const int idxAn = mylist[min((c + 1) * G2 + gg, cnt - 1)];
            const int idxBn = mylist[min((c + 1) * G2 + gg + 16, cnt - 1)];
            {
                const int qi = c * G2 + gg;
                const float4 e0 = pv[(size_t)(bN + idxA) * 2 + 0];
                const float4 e1 = pv[(size_t)(bN + idxA) * 2 + 1];
                const float dyn = (fy - e0.y) * e0.w;
                const float dxn = (fx - e0.x) * e0.z;
                const float dist = dyn * dyn + dxn * dxn;
                float gv = 0.f;
                if (dist < 9.f) gv = __expf(-0.5f * dist) * e1.x;
                if (qi >= cnt) gv = 0.f;
                gws[buf][gg * 20 + pxi] = gv;
                densp += gv;
                uncp  += gv * e1.y;

                const float4 f0 = pv[(size_t)(bN + idxB) * 2 + 0];
                const float4 f1 = pv[(size_t)(bN + idxB) * 2 + 1];
                const float dyn2 = (fy - f0.y) * f0.w;
                const float dxn2 = (fx - f0.x) * f0.z;
                const float dist2 = dyn2 * dyn2 + dxn2 * dxn2;
                float gv2 = 0.f;
                if (dist2 < 9.f) gv2 = __expf(-0.5f * dist2) * f1.x;
                if (qi + 16 >= cnt) gv2 = 0.f;
                gws[buf][(gg + 16) * 20 + pxi] = gv2;
                densp += gv2;
                uncp  += gv2 * f1.y;
            }
            __syncthreads();
            if (c + 1 < nchunks) {
#pragma unroll
                for (int j = 0; j < 2; ++j) {
                    {
                        const int nLo = __shfl(idxAn, 32 * j);
                        const int nHi = __shfl(idxAn, 32 * j + 16);
                        const int n = (lane < 32) ? nLo : nHi;
                        gl_lds16u(feats + ((size_t)(bN + n) << 8) + (lane & 31) * 8,
                                  &feats_bf[buf ^ 1][(4 * wid + 2 * j) * 256] + lane * 8);
                    }
                    {
                        const int nLo = __shfl(idxBn, 32 * j);
                        const int nHi = __shfl(idxBn, 32 * j + 16);
                        const int n = (lane < 32) ? nLo : nHi;
                        gl_lds16u(feats + ((size_t)(bN + n) << 8) + (lane & 31) * 8,
                                  &feats_bf[buf ^ 1][(4 * wid + 16 + 2 * j) * 256] + lane * 8);
                    }
                }
            }
#pragma unroll 4
            for (int it = 0; it < 16; ++it) {
                const int qq = 2 * it + qo;
                const uint4 fw = *(const uint4*)&feats_bf[buf][qq * 256 + cho * 8];
                const float4 g4 = *(const float4*)&gws[buf][qq * 20 + 4 * pg];
                float fch[8];
                fch[0] = __uint_as_float(fw.x << 16);
                fch[1] = __uint_as_float(fw.x & 0xffff0000u);
                fch[2] = __uint_as_float(fw.y << 16);
                fch[3] = __uint_as_float(fw.y & 0xffff0000u);
                fch[4] = __uint_as_float(fw.z << 16);
                fch[5] = __uint_as_float(fw.z & 0xffff0000u);
                fch[6] = __uint_as_float(fw.w << 16);
                fch[7] = __uint_as_float(fw.w & 0xffff0000u);
#pragma unroll
                for (int cc = 0; cc < 8; ++cc) {
                    acc[cc][0] = fmaf(fch[cc], g4.x, acc[cc][0]);
                    acc[cc][1] = fmaf(fch[cc], g4.y, acc[cc][1]);
                    acc[cc][2] = fmaf(fch[cc], g4.z, acc[cc][2]);
                    acc[cc][3] = fmaf(fch[cc], g4.w, acc[cc][3]);
                }
            }
            idxA = idxAn;
            idxB = idxBn;
        }
    }

    __syncthreads();
    float* red_d = (float*)&feats_bf[0][0];   // 16 x 20
    float* red_u = red_d + 512;
    red_d[gg * 20 + pxi] = densp;
    red_u[gg * 20 + pxi] = uncp;
    __syncthreads();
    for (int s = 8; s > 0; s >>= 1) {
        if (gg < s) {
            red_d[gg * 20 + pxi] += red_d[(gg + s) * 20 + pxi];
            red_u[gg * 20 + pxi] += red_u[(gg + s) * 20 + pxi];
        }
        __syncthreads();
    }

    float rinv[4];
#pragma unroll
    for (int k = 0; k < 4; ++k) rinv[k] = 1.f / fmaxf(red_d[4 * pg + k], 1e-6f);
    if (tid < TW) {
        const size_t pix = ((size_t)b * H_ + y) * W_ + x0 + tid;
        float* unc_o = out + (size_t)B_ * C_ * H_ * W_;
        float* den_o = unc_o + (size_t)B_ * H_ * W_;
        const float d = fmaxf(red_d[tid], 1e-6f);
        unc_o[pix] = red_u[tid] / d;
        den_o[pix] = d;
    }
    __syncthreads();

    float4* mb = (float4*)&feats_bf[0][0];
    if (qo == 1) {
#pragma unroll
        for (int cc = 0; cc < 8; ++cc)
            mb[cc * 128 + pos] = make_float4(acc[cc][0], acc[cc][1],
                                             acc[cc][2], acc[cc][3]);
    }
    __syncthreads();
    if (qo == 0) {
#pragma unroll
        for (int cc = 0; cc < 8; ++cc) {
            const float4 o = mb[cc * 128 + pos];
            float4 v;
            v.x = (acc[cc][0] + o.x) * rinv[0];
            v.y = (acc[cc][1] + o.y) * rinv[1];
            v.z = (acc[cc][2] + o.z) * rinv[2];
            v.w = (acc[cc][3] + o.w) * rinv[3];
            const int ch = cho * 8 + cc;
            *(float4*)(out + (((size_t)b * C_ + ch) * H_ + y) * W_ + x0 + 4 * pg) = v;
        }
    }
}

// ---------------------------------------------------------------------------
extern "C" void kernel_launch(void* const* d_in, const int* in_sizes, int n_in,
                              void* d_out, int out_size, void* d_ws, size_t ws_size,
                              hipStream_t stream)
{
    const float* g    = (const float*)d_in[0];
    const float* intr = (const float*)d_in[1];
    const float* w1   = (const float*)d_in[2];
    const float* b1   = (const float*)d_in[3];
    const float* w2   = (const float*)d_in[4];
    const float* b2   = (const float*)d_in[5];
    const float* w3   = (const float*)d_in[6];
    const float* b3   = (const float*)d_in[7];
    const float* fw1  = (const float*)d_in[8];
    const float* fb1  = (const float*)d_in[9];
    const float* fw2  = (const float*)d_in[10];
    const float* fb2  = (const float*)d_in[11];

    char* base = (char*)d_ws;
    const int rows = B_ * N_;                               // 4096
    ushort_t* ftb = (ushort_t*)base;                        // 2 MB bf16 [n][ch]
    float* pp     = (float*)(base + (size_t)rows * C_ * 2); // 128 KB
    int*   counts = (int*)(pp + (size_t)8 * rows);          // 1408 ints
    int*   lists  = counts + NTILES;                        // 1408*1024 ints
    short* wt3    = (short*)(lists + (size_t)NTILES * CAP); // 128*256 bf16
    short* wt4    = wt3 + 128 * 256;                        // 256*256 bf16
    short* wt5    = wt4 + 256 * 256;                        // 256*256 bf16

    prep_kernel<<<dim3(256), dim3(256), 0, stream>>>(w3, fw1, fw2, wt3, wt4, wt5, counts);
    pb_mlp_kernel<<<dim3(768), dim3(256), 0, stream>>>(
        g, intr, w1, b1, w2, b2, wt3, b3, wt4, fb1, wt5, fb2, ftb, pp, counts, lists);
    splat_kernel<<<dim3(NTILES), dim3(256), 0, stream>>>(pp, lists, counts, ftb, (float*)d_out);
}